// Round 9
// baseline (986.953 us; speedup 1.0000x reference)
//
#include <hip/hip_runtime.h>
#include <math.h>

#define NCLS 9

typedef __attribute__((ext_vector_type(8))) short short8;
typedef __attribute__((ext_vector_type(4))) float f32x4;

__device__ __forceinline__ unsigned short f2bf(float f) {
    unsigned int u = __float_as_uint(f);
    return (unsigned short)((u + 0x7fffu + ((u >> 16) & 1u)) >> 16);  // RNE
}

__device__ __forceinline__ short8 as_s8(uint4 v) {
    union { uint4 u; short8 s; } x; x.u = v; return x.s;
}

__device__ __forceinline__ float fast_tanh(float x) {
    // tanh(x) = 1 - 2/(2^(x*2*log2e) + 1); saturates correctly at +/-1
    float s = x * 2.885390081777927f;
    float e, r;
    asm("v_exp_f32 %0, %1" : "=v"(e) : "v"(s));
    asm("v_rcp_f32 %0, %1" : "=v"(r) : "v"(e + 1.0f));
    return fmaf(-2.0f, r, 1.0f);
}

// Fused 2-layer persistent MFMA RNN, C=64 cols/wave with AGPR-pinned U.
// 32 blocks x 16 batch rows, 256 threads (4 waves, 1 wave/SIMD).
// Wave w owns 64 output cols as 4 B-tiles; tile (u,v) covers cols
// w*64 + u*32 + 2c + v (c = lane&15) -> per-row output pairs pack to one
// v_cvt_pk_bf16_f32 + one b32 LDS write.
//
// KEY EXPERIMENT vs R7: the 128 bfrag registers are pinned ONCE (not per
// iteration) into the AGPR class via "+a" asm. gfx950 MFMA reads B operands
// from AGPR natively; remat of an AGPR-class value requires reload +
// v_accvgpr_write, which the allocator avoids -> U finally stays resident
// (R1/R3/R4/R7 failure mode), and VGPR-class pressure drops to ~110.
//
// h LDS layout (R6): 512 cells x 16B; cell (kk,g2,m) at index
// kk*64+g2*16+(m ^ ((4*kk+g2)&15)).
//  - A-read (per kk): contiguous permuted 1KB -> conflict-free ds_read_b128.
//  - h-write: b32, exactly 2-way bank aliasing (free).
// DS traffic: 4 waves x 8KB = 32KB/step (half of R6/R8).
__global__ __launch_bounds__(256, 1) void rnn_fused_kernel(
    const float* __restrict__ x,     // [B, 1024]
    const float* __restrict__ W1, const float* __restrict__ U1, const float* __restrict__ b1,
    const float* __restrict__ W2, const float* __restrict__ U2, const float* __restrict__ b2,
    float* __restrict__ h2out)       // [B, 256]
{
    const int tid  = threadIdx.x;
    const int w    = tid >> 6;    // wave 0..3
    const int lane = tid & 63;
    const int g    = lane >> 4;
    const int l16  = lane & 15;
    const int b0   = blockIdx.x << 4;

    __shared__ uint4 hbuf[2][512];       // 2 x 8KB, cell layout above
    __shared__ float xall[1024][16];     // 64KB: x staged [t][row]
    __shared__ float seq2[256][16];      // 16KB: layer-2 input [col][row]

    // ---- stage all of x (once) + zero h buffer 0 ----
    {
        const float4* x4 = (const float4*)x;
        #pragma unroll
        for (int i = 0; i < 16; ++i) {
            const int idx = tid + i * 256;
            const int row = idx >> 8, tq = idx & 255;
            const float4 v = x4[(b0 + row) * 256 + tq];
            xall[tq * 4 + 0][row] = v.x;
            xall[tq * 4 + 1][row] = v.y;
            xall[tq * 4 + 2][row] = v.z;
            xall[tq * 4 + 3][row] = v.w;
        }
        for (int idx = tid; idx < 2048; idx += 256)
            ((unsigned int*)hbuf[0])[idx] = 0u;
    }

    // ---- hoisted LDS byte offsets ----
    int rd_off[8];
    #pragma unroll
    for (int kk = 0; kk < 8; ++kk)
        rd_off[kk] = ((kk * 64 + g * 16) + (l16 ^ ((kk * 4 + g) & 15))) << 4;
    const int q = l16 >> 2, s4 = l16 & 3;
    int wr_off[4][2];
    #pragma unroll
    for (int r = 0; r < 4; ++r) {
        #pragma unroll
        for (int u = 0; u < 2; ++u) {
            const int K = 2 * w + u;
            const int m = 4 * g + r;
            wr_off[r][u] = ((K * 64 + q * 16 + (m ^ ((4 * K + q) & 15))) << 4) + 4 * s4;
        }
    }
    char* const hbase = (char*)hbuf;

#pragma unroll 1
    for (int p = 0; p < 2; ++p) {
        const float* W    = p ? W2 : W1;
        const float* U    = p ? U2 : U1;
        const float* bias = p ? b2 : b1;
        const int    T    = p ? 256 : 1024;

        // ---- B-fragments (bf16); tile (u,v): col = w*64 + u*32 + 2c + v ----
        uint4 bfrag[2][2][8];
        #pragma unroll
        for (int u = 0; u < 2; ++u) {
            #pragma unroll
            for (int v = 0; v < 2; ++v) {
                const int col = w * 64 + u * 32 + 2 * l16 + v;
                #pragma unroll
                for (int kk = 0; kk < 8; ++kk) {
                    unsigned int d[4];
                    #pragma unroll
                    for (int pr = 0; pr < 4; ++pr) {
                        const int k0 = kk * 32 + g * 8 + 2 * pr;
                        d[pr] = (unsigned)f2bf(U[k0 * 256 + col])
                              | ((unsigned)f2bf(U[(k0 + 1) * 256 + col]) << 16);
                    }
                    bfrag[u][v][kk] = make_uint4(d[0], d[1], d[2], d[3]);
                }
            }
        }
        // ---- ONE-TIME AGPR pin (no per-iteration fence) ----
        #pragma unroll
        for (int u = 0; u < 2; ++u)
            #pragma unroll
            for (int v = 0; v < 2; ++v)
                #pragma unroll
                for (int kk = 0; kk < 8; ++kk)
                    asm volatile("" : "+a"(bfrag[u][v][kk].x), "+a"(bfrag[u][v][kk].y),
                                      "+a"(bfrag[u][v][kk].z), "+a"(bfrag[u][v][kk].w));

        // W/bias for col pairs (u): cols w*64 + u*32 + 2*l16 + {0,1}
        const float2 wv[2] = { *(const float2*)&W[w * 64 + 2 * l16],
                               *(const float2*)&W[w * 64 + 32 + 2 * l16] };
        const float2 bv[2] = { *(const float2*)&bias[w * 64 + 2 * l16],
                               *(const float2*)&bias[w * 64 + 32 + 2 * l16] };

        if (p == 1) {
            for (int idx = tid; idx < 2048; idx += 256)
                ((unsigned int*)hbuf[0])[idx] = 0u;
        }
        __syncthreads();

        // prefetch sv for t=0 (xall/seq2 static during loop)
        float4 svc = p ? *(const float4*)&seq2[0][4 * g]
                       : *(const float4*)&xall[0][4 * g];

        for (int t = 0; t < T; ++t) {
            char* const hcur = hbase + ((t & 1) << 13);
            char* const hnxt = hbase + (((t & 1) ^ 1) << 13);

            // A-fragments: 8 x ds_read_b128, conflict-free
            uint4 a[8];
            #pragma unroll
            for (int kk = 0; kk < 8; ++kk)
                a[kk] = *(const uint4*)(hcur + rd_off[kk]);

            const float svr[4] = {svc.x, svc.y, svc.z, svc.w};

            // accE init = input projection + bias (overlaps ds_read latency)
            f32x4 accE[2][2], accO[2][2];
            #pragma unroll
            for (int u = 0; u < 2; ++u) {
                #pragma unroll
                for (int r = 0; r < 4; ++r) {
                    accE[u][0][r] = fmaf(svr[r], wv[u].x, bv[u].x);
                    accE[u][1][r] = fmaf(svr[r], wv[u].y, bv[u].y);
                }
                accO[u][0] = (f32x4){0.f, 0.f, 0.f, 0.f};
                accO[u][1] = (f32x4){0.f, 0.f, 0.f, 0.f};
            }

            // 8 independent 4-deep MFMA chains (4 tiles x even/odd kk)
            #pragma unroll
            for (int kp = 0; kp < 4; ++kp) {
                #pragma unroll
                for (int u = 0; u < 2; ++u)
                    #pragma unroll
                    for (int v = 0; v < 2; ++v) {
                        accE[u][v] = __builtin_amdgcn_mfma_f32_16x16x32_bf16(
                            as_s8(a[2 * kp]), as_s8(bfrag[u][v][2 * kp]), accE[u][v], 0, 0, 0);
                        accO[u][v] = __builtin_amdgcn_mfma_f32_16x16x32_bf16(
                            as_s8(a[2 * kp + 1]), as_s8(bfrag[u][v][2 * kp + 1]), accO[u][v], 0, 0, 0);
                    }
            }

            // prefetch sv for t+1 (static LDS, safe before the barrier)
            {
                const int tn = (t + 1 < T) ? t + 1 : t;
                svc = p ? *(const float4*)&seq2[tn][4 * g]
                        : *(const float4*)&xall[tn][4 * g];
            }

            #pragma unroll
            for (int r = 0; r < 4; ++r) {
                #pragma unroll
                for (int u = 0; u < 2; ++u) {
                    const float h0 = fast_tanh(accE[u][0][r] + accO[u][0][r]);
                    const float h1 = fast_tanh(accE[u][1][r] + accO[u][1][r]);
                    unsigned pk;
                    asm("v_cvt_pk_bf16_f32 %0, %1, %2" : "=v"(pk) : "v"(h0), "v"(h1));
                    *(unsigned int*)(hnxt + wr_off[r][u]) = pk;

                    if (t == T - 1) {
                        const int m    = 4 * g + r;
                        const int colb = w * 64 + u * 32 + 2 * l16;
                        if (p == 0) {
                            seq2[colb][m]     = h0;
                            seq2[colb + 1][m] = h1;
                        } else {
                            *(float2*)&h2out[(b0 + m) * 256 + colb] = make_float2(h0, h1);
                        }
                    }
                }
            }
            __syncthreads();
        }
    }
}

// Tiny MLP head: one block per batch row, 128 threads.
__global__ __launch_bounds__(128) void mlp_kernel(
    const float* __restrict__ h2,
    const float* __restrict__ Wd1, const float* __restrict__ bd1,
    const float* __restrict__ Wd2, const float* __restrict__ bd2,
    const float* __restrict__ Wd3, const float* __restrict__ bd3,
    const float* __restrict__ Wd4, const float* __restrict__ bd4,
    float* __restrict__ out)
{
    const int b   = blockIdx.x;
    const int tid = threadIdx.x;

    __shared__ float hin[256];
    __shared__ float z1[128];
    __shared__ float z2[64];
    __shared__ float z3[32];

    hin[tid]       = h2[b * 256 + tid];
    hin[tid + 128] = h2[b * 256 + tid + 128];
    __syncthreads();

    {
        float a = bd1[tid];
#pragma unroll 8
        for (int i = 0; i < 256; ++i) a += hin[i] * Wd1[i * 128 + tid];
        z1[tid] = fmaxf(a, 0.0f);
    }
    __syncthreads();
    if (tid < 64) {
        float a = bd2[tid];
#pragma unroll 8
        for (int i = 0; i < 128; ++i) a += z1[i] * Wd2[i * 64 + tid];
        z2[tid] = fmaxf(a, 0.0f);
    }
    __syncthreads();
    if (tid < 32) {
        float a = bd3[tid];
#pragma unroll 8
        for (int i = 0; i < 64; ++i) a += z2[i] * Wd3[i * 32 + tid];
        z3[tid] = fmaxf(a, 0.0f);
    }
    __syncthreads();
    if (tid < NCLS) {
        float a = bd4[tid];
#pragma unroll
        for (int i = 0; i < 32; ++i) a += z3[i] * Wd4[i * NCLS + tid];
        out[b * NCLS + tid] = a;
    }
}

extern "C" void kernel_launch(void* const* d_in, const int* in_sizes, int n_in,
                              void* d_out, int out_size, void* d_ws, size_t ws_size,
                              hipStream_t stream) {
    const float* x   = (const float*)d_in[0];
    const float* W1  = (const float*)d_in[1];
    const float* U1  = (const float*)d_in[2];
    const float* b1  = (const float*)d_in[3];
    const float* W2  = (const float*)d_in[4];
    const float* U2  = (const float*)d_in[5];
    const float* b2  = (const float*)d_in[6];
    const float* Wd1 = (const float*)d_in[7];
    const float* bd1 = (const float*)d_in[8];
    const float* Wd2 = (const float*)d_in[9];
    const float* bd2 = (const float*)d_in[10];
    const float* Wd3 = (const float*)d_in[11];
    const float* bd3 = (const float*)d_in[12];
    const float* Wd4 = (const float*)d_in[13];
    const float* bd4 = (const float*)d_in[14];

    float* out = (float*)d_out;
    float* h2  = (float*)d_ws;        // 512*256 fp32

    rnn_fused_kernel<<<32, 256, 0, stream>>>(x, W1, U1, b1, W2, U2, b2, h2);
    mlp_kernel<<<512, 128, 0, stream>>>(h2, Wd1, bd1, Wd2, bd2, Wd3, bd3, Wd4, bd4, out);
}

// Round 10
// 826.750 us; speedup vs baseline: 1.1938x; 1.1938x over previous
//
#include <hip/hip_runtime.h>
#include <math.h>

#define NCLS 9

typedef __attribute__((ext_vector_type(8))) short short8;
typedef __attribute__((ext_vector_type(4))) float f32x4;

__device__ __forceinline__ unsigned short f2bf(float f) {
    unsigned int u = __float_as_uint(f);
    return (unsigned short)((u + 0x7fffu + ((u >> 16) & 1u)) >> 16);  // RNE
}

__device__ __forceinline__ short8 as_s8(uint4 v) {
    union { uint4 u; short8 s; } x; x.u = v; return x.s;
}

__device__ __forceinline__ float fast_tanh(float x) {
    // tanh(x) = 1 - 2/(2^(x*2*log2e) + 1); saturates correctly at +/-1
    float s = x * 2.885390081777927f;
    float e, r;
    asm("v_exp_f32 %0, %1" : "=v"(e) : "v"(s));
    asm("v_rcp_f32 %0, %1" : "=v"(r) : "v"(e + 1.0f));
    return fmaf(-2.0f, r, 1.0f);
}

// Fused 2-layer persistent MFMA RNN (R8 structure + 2-step unroll + setprio).
// 32 blocks x 16 batch rows, 512 threads (8 waves, 2 waves/SIMD).
// Wave w owns 32 output cols (2 B-tiles, 64 pinned VGPR), paired-column map
// col = w*32 + 2c + t2 -> per-row output pair packs to one v_cvt_pk_bf16_f32
// + one b32 LDS write.
//
// h LDS layout: 512 cells x 16B; cell (kk,g2,m) holds k=kk*32+g2*8+e of row m
// at index kk*64+g2*16+(m ^ ((4*kk+g2)&15)).
//  - A-read (per kk): contiguous permuted 1KB -> conflict-free ds_read_b128.
//  - h-write: b32, exactly 2-way bank aliasing (free).
//
// R10 changes: 2-step unrolled loop (compile-time buffer ptrs, sv ping-pong,
// no clamp-select on the prefetch index), s_setprio(1) around the MFMA
// cluster (the two waves per SIMD drift into different phases within a
// barrier interval -- the role-split regime where setprio measured positive).
__global__ __launch_bounds__(512, 2) void rnn_fused_kernel(
    const float* __restrict__ x,     // [B, 1024]
    const float* __restrict__ W1, const float* __restrict__ U1, const float* __restrict__ b1,
    const float* __restrict__ W2, const float* __restrict__ U2, const float* __restrict__ b2,
    float* __restrict__ h2out)       // [B, 256]
{
    const int tid  = threadIdx.x;
    const int w    = tid >> 6;
    const int lane = tid & 63;
    const int g    = lane >> 4;
    const int l16  = lane & 15;
    const int b0   = blockIdx.x << 4;

    __shared__ uint4 hbuf[2][512];       // 2 x 8KB, cell layout above
    __shared__ float xall[1024][16];     // 64KB: x staged [t][row]
    __shared__ float seq2[256][16];      // 16KB: layer-2 input [col][row]

    // ---- stage all of x (once) + zero h buffer 0 ----
    {
        const float4* x4 = (const float4*)x;
        #pragma unroll
        for (int i = 0; i < 8; ++i) {
            const int idx = tid + i * 512;
            const int row = idx >> 8, tq = idx & 255;
            const float4 v = x4[(b0 + row) * 256 + tq];
            xall[tq * 4 + 0][row] = v.x;
            xall[tq * 4 + 1][row] = v.y;
            xall[tq * 4 + 2][row] = v.z;
            xall[tq * 4 + 3][row] = v.w;
        }
        for (int idx = tid; idx < 2048; idx += 512)
            ((unsigned int*)hbuf[0])[idx] = 0u;
    }

    // ---- hoisted LDS byte offsets ----
    int rd_off[8];
    #pragma unroll
    for (int kk = 0; kk < 8; ++kk)
        rd_off[kk] = ((kk * 64 + g * 16) + (l16 ^ ((kk * 4 + g) & 15))) << 4;
    const int q = l16 >> 2, s4 = l16 & 3;
    int wr_off[4];
    #pragma unroll
    for (int r = 0; r < 4; ++r) {
        const int m = 4 * g + r;
        wr_off[r] = (((w * 64 + q * 16) + (m ^ ((4 * w + q) & 15))) << 4) + 4 * s4;
    }
    const int col0 = w * 32 + 2 * l16;
    char* const hb0 = (char*)hbuf;
    char* const hb1 = (char*)hbuf + 8192;

#pragma unroll 1
    for (int p = 0; p < 2; ++p) {
        const float* W    = p ? W2 : W1;
        const float* U    = p ? U2 : U1;
        const float* bias = p ? b2 : b1;
        const int    T    = p ? 256 : 1024;

        // ---- B-fragments (bf16, pinned registers); col = w*32 + 2c + t2 ----
        uint4 bfrag[2][8];
        #pragma unroll
        for (int t2 = 0; t2 < 2; ++t2) {
            #pragma unroll
            for (int kk = 0; kk < 8; ++kk) {
                unsigned int d[4];
                #pragma unroll
                for (int pr = 0; pr < 4; ++pr) {
                    const int k0 = kk * 32 + g * 8 + 2 * pr;
                    d[pr] = (unsigned)f2bf(U[k0 * 256 + col0 + t2])
                          | ((unsigned)f2bf(U[(k0 + 1) * 256 + col0 + t2]) << 16);
                }
                bfrag[t2][kk] = make_uint4(d[0], d[1], d[2], d[3]);
            }
        }
        #pragma unroll
        for (int t2 = 0; t2 < 2; ++t2)
            #pragma unroll
            for (int kk = 0; kk < 8; ++kk)
                asm volatile("" : "+v"(bfrag[t2][kk].x), "+v"(bfrag[t2][kk].y),
                                  "+v"(bfrag[t2][kk].z), "+v"(bfrag[t2][kk].w));

        const float2 wv2 = *(const float2*)&W[col0];
        const float2 bv2 = *(const float2*)&bias[col0];

        if (p == 1) {
            // re-zero h buffer 0 for layer 2
            for (int idx = tid; idx < 2048; idx += 512)
                ((unsigned int*)hbuf[0])[idx] = 0u;
        }
        __syncthreads();

        // sv ping-pong registers (xall/seq2 are static during the loop)
        float4 sv0 = p ? *(const float4*)&seq2[0][4 * g]
                       : *(const float4*)&xall[0][4 * g];
        float4 sv1;

#define RNN_STEP(HCUR, HNXT, SVC, SVN, TT, TN)                                   \
        {                                                                        \
            uint4 a[8];                                                          \
            _Pragma("unroll")                                                    \
            for (int kk = 0; kk < 8; ++kk)                                       \
                a[kk] = *(const uint4*)((HCUR) + rd_off[kk]);                    \
            const float svr[4] = {(SVC).x, (SVC).y, (SVC).z, (SVC).w};           \
            f32x4 aA0, aA1;                                                      \
            f32x4 aB0 = {0.f, 0.f, 0.f, 0.f}, aB1 = {0.f, 0.f, 0.f, 0.f};        \
            _Pragma("unroll")                                                    \
            for (int r = 0; r < 4; ++r) {                                        \
                aA0[r] = fmaf(svr[r], wv2.x, bv2.x);                             \
                aA1[r] = fmaf(svr[r], wv2.y, bv2.y);                             \
            }                                                                    \
            __builtin_amdgcn_s_setprio(1);                                       \
            _Pragma("unroll")                                                    \
            for (int kp = 0; kp < 4; ++kp) {                                     \
                aA0 = __builtin_amdgcn_mfma_f32_16x16x32_bf16(                   \
                    as_s8(a[2 * kp]), as_s8(bfrag[0][2 * kp]), aA0, 0, 0, 0);    \
                aA1 = __builtin_amdgcn_mfma_f32_16x16x32_bf16(                   \
                    as_s8(a[2 * kp]), as_s8(bfrag[1][2 * kp]), aA1, 0, 0, 0);    \
                aB0 = __builtin_amdgcn_mfma_f32_16x16x32_bf16(                   \
                    as_s8(a[2 * kp + 1]), as_s8(bfrag[0][2 * kp + 1]), aB0, 0, 0, 0); \
                aB1 = __builtin_amdgcn_mfma_f32_16x16x32_bf16(                   \
                    as_s8(a[2 * kp + 1]), as_s8(bfrag[1][2 * kp + 1]), aB1, 0, 0, 0); \
            }                                                                    \
            __builtin_amdgcn_s_setprio(0);                                       \
            (SVN) = p ? *(const float4*)&seq2[(TN)][4 * g]                       \
                      : *(const float4*)&xall[(TN)][4 * g];                      \
            _Pragma("unroll")                                                    \
            for (int r = 0; r < 4; ++r) {                                        \
                const float h0 = fast_tanh(aA0[r] + aB0[r]);                     \
                const float h1 = fast_tanh(aA1[r] + aB1[r]);                     \
                unsigned pk;                                                     \
                asm("v_cvt_pk_bf16_f32 %0, %1, %2" : "=v"(pk) : "v"(h0), "v"(h1)); \
                *(unsigned int*)((HNXT) + wr_off[r]) = pk;                       \
                if ((TT) == T - 1) {                                             \
                    const int m = 4 * g + r;                                     \
                    if (p == 0) {                                                \
                        seq2[col0][m]     = h0;                                  \
                        seq2[col0 + 1][m] = h1;                                  \
                    } else {                                                     \
                        *(float2*)&h2out[(b0 + m) * 256 + col0] =                \
                            make_float2(h0, h1);                                 \
                    }                                                            \
                }                                                                \
            }                                                                    \
            __syncthreads();                                                     \
        }

        // T is even: 2-step unrolled, compile-time buffer ping-pong
        for (int t = 0; t < T; t += 2) {
            RNN_STEP(hb0, hb1, sv0, sv1, t, t + 1);
            RNN_STEP(hb1, hb0, sv1, sv0, t + 1, (t + 2 < T) ? t + 2 : 0);
        }
#undef RNN_STEP
    }
}

// Tiny MLP head: one block per batch row, 128 threads.
__global__ __launch_bounds__(128) void mlp_kernel(
    const float* __restrict__ h2,
    const float* __restrict__ Wd1, const float* __restrict__ bd1,
    const float* __restrict__ Wd2, const float* __restrict__ bd2,
    const float* __restrict__ Wd3, const float* __restrict__ bd3,
    const float* __restrict__ Wd4, const float* __restrict__ bd4,
    float* __restrict__ out)
{
    const int b   = blockIdx.x;
    const int tid = threadIdx.x;

    __shared__ float hin[256];
    __shared__ float z1[128];
    __shared__ float z2[64];
    __shared__ float z3[32];

    hin[tid]       = h2[b * 256 + tid];
    hin[tid + 128] = h2[b * 256 + tid + 128];
    __syncthreads();

    {
        float a = bd1[tid];
#pragma unroll 8
        for (int i = 0; i < 256; ++i) a += hin[i] * Wd1[i * 128 + tid];
        z1[tid] = fmaxf(a, 0.0f);
    }
    __syncthreads();
    if (tid < 64) {
        float a = bd2[tid];
#pragma unroll 8
        for (int i = 0; i < 128; ++i) a += z1[i] * Wd2[i * 64 + tid];
        z2[tid] = fmaxf(a, 0.0f);
    }
    __syncthreads();
    if (tid < 32) {
        float a = bd3[tid];
#pragma unroll 8
        for (int i = 0; i < 64; ++i) a += z2[i] * Wd3[i * 32 + tid];
        z3[tid] = fmaxf(a, 0.0f);
    }
    __syncthreads();
    if (tid < NCLS) {
        float a = bd4[tid];
#pragma unroll
        for (int i = 0; i < 32; ++i) a += z3[i] * Wd4[i * NCLS + tid];
        out[b * NCLS + tid] = a;
    }
}

extern "C" void kernel_launch(void* const* d_in, const int* in_sizes, int n_in,
                              void* d_out, int out_size, void* d_ws, size_t ws_size,
                              hipStream_t stream) {
    const float* x   = (const float*)d_in[0];
    const float* W1  = (const float*)d_in[1];
    const float* U1  = (const float*)d_in[2];
    const float* b1  = (const float*)d_in[3];
    const float* W2  = (const float*)d_in[4];
    const float* U2  = (const float*)d_in[5];
    const float* b2  = (const float*)d_in[6];
    const float* Wd1 = (const float*)d_in[7];
    const float* bd1 = (const float*)d_in[8];
    const float* Wd2 = (const float*)d_in[9];
    const float* bd2 = (const float*)d_in[10];
    const float* Wd3 = (const float*)d_in[11];
    const float* bd3 = (const float*)d_in[12];
    const float* Wd4 = (const float*)d_in[13];
    const float* bd4 = (const float*)d_in[14];

    float* out = (float*)d_out;
    float* h2  = (float*)d_ws;        // 512*256 fp32

    rnn_fused_kernel<<<32, 512, 0, stream>>>(x, W1, U1, b1, W2, U2, b2, h2);
    mlp_kernel<<<512, 128, 0, stream>>>(h2, Wd1, bd1, Wd2, bd2, Wd3, bd3, Wd4, bd4, out);
}

// Round 11
// 595.423 us; speedup vs baseline: 1.6576x; 1.3885x over previous
//
#include <hip/hip_runtime.h>
#include <math.h>

#define NCLS 9

typedef __attribute__((ext_vector_type(8))) short short8;
typedef __attribute__((ext_vector_type(4))) float f32x4;

__device__ __forceinline__ unsigned short f2bf(float f) {
    unsigned int u = __float_as_uint(f);
    return (unsigned short)((u + 0x7fffu + ((u >> 16) & 1u)) >> 16);  // RNE
}

__device__ __forceinline__ short8 as_s8(uint4 v) {
    union { uint4 u; short8 s; } x; x.u = v; return x.s;
}

__device__ __forceinline__ float fast_tanh(float x) {
    // tanh(x) = 1 - 2/(2^(x*2*log2e) + 1); saturates correctly at +/-1
    float s = x * 2.885390081777927f;
    float e, r;
    asm("v_exp_f32 %0, %1" : "=v"(e) : "v"(s));
    asm("v_rcp_f32 %0, %1" : "=v"(r) : "v"(e + 1.0f));
    return fmaf(-2.0f, r, 1.0f);
}

// Fused 2-layer persistent MFMA RNN, M=2 rows/block, 256 blocks (full chip).
// 512 threads (8 waves, 2/SIMD). Wave w owns 32 output cols (2 B-tiles,
// 64 pinned VGPR), paired-column map col = w*32 + 2c + t2.
//
// ROW-DUPLICATION TRICK: the MFMA A-operand wants rows lane&15; with only 2
// real rows, lane (g,l16) reads row (l16&1) -- 8 lanes share each address
// (same-address broadcast = free) -- so A rows 2..15 are duplicates of 0..1,
// C rows 2..15 are consistent duplicates, and only C rows 0..1 (g==0,
// r∈{0,1}) are kept. DS A-traffic per instr: 128B distinct vs 1KB at M=16.
//
// h LDS: 64 cells x 16B per buffer; cell (kk,g2,m) = idx kk*8+g2*2+m holds
// k = kk*32+g2*8+0..7 of row m.
//  - A-read (per kk): 8 distinct contiguous cells, 1 word/bank, broadcast x8.
//  - h-write (g==0 lanes): bank = g2w*8 + 4r + s4 -> 16 distinct banks,
//    conflict-free, 2 x b32 per lane.
// Per-CU DS/step ~450 cyc vs R8's ~1050; epilogue halves (r<2 only).
__global__ __launch_bounds__(512, 2) void rnn_fused_kernel(
    const float* __restrict__ x,     // [B, 1024]
    const float* __restrict__ W1, const float* __restrict__ U1, const float* __restrict__ b1,
    const float* __restrict__ W2, const float* __restrict__ U2, const float* __restrict__ b2,
    float* __restrict__ h2out)       // [B, 256]
{
    const int tid  = threadIdx.x;
    const int w    = tid >> 6;
    const int lane = tid & 63;
    const int g    = lane >> 4;
    const int l16  = lane & 15;
    const int b0   = blockIdx.x << 1;   // 2 rows per block

    __shared__ uint4  hbuf[2][64];    // 2 x 1KB, cell layout above
    __shared__ float2 xall[1024];     // 8KB: x staged [t]{row0,row1}
    __shared__ float2 seq2[256];      // 2KB: layer-2 input [col]{row0,row1}

    // ---- stage all of x (once) + zero both h buffers ----
    {
        const float4* x4 = (const float4*)x;
        const int row = tid >> 8, tq = tid & 255;      // 512 threads = 2x256
        const float4 v = x4[(b0 + row) * 256 + tq];
        ((float*)&xall[tq * 4 + 0])[row] = v.x;
        ((float*)&xall[tq * 4 + 1])[row] = v.y;
        ((float*)&xall[tq * 4 + 2])[row] = v.z;
        ((float*)&xall[tq * 4 + 3])[row] = v.w;
        ((unsigned int*)hbuf)[tid] = 0u;               // 512 u32 = both buffers
    }

    // ---- hoisted LDS byte offsets ----
    int rd_off[8];
    #pragma unroll
    for (int kk = 0; kk < 8; ++kk)
        rd_off[kk] = (kk * 8 + g * 2 + (l16 & 1)) << 4;
    const int g2w = (l16 >> 2) & 3, s4 = l16 & 3;
    int wr_off[2];
    #pragma unroll
    for (int r = 0; r < 2; ++r)
        wr_off[r] = ((w * 8 + g2w * 2 + r) << 4) + 4 * s4;
    const int col0 = w * 32 + 2 * l16;
    char* const hbase = (char*)hbuf;

#pragma unroll 1
    for (int p = 0; p < 2; ++p) {
        const float* W    = p ? W2 : W1;
        const float* U    = p ? U2 : U1;
        const float* bias = p ? b2 : b1;
        const int    T    = p ? 256 : 1024;

        // ---- B-fragments (bf16, pinned registers); col = w*32 + 2c + t2 ----
        uint4 bfrag[2][8];
        #pragma unroll
        for (int t2 = 0; t2 < 2; ++t2) {
            #pragma unroll
            for (int kk = 0; kk < 8; ++kk) {
                unsigned int d[4];
                #pragma unroll
                for (int pr = 0; pr < 4; ++pr) {
                    const int k0 = kk * 32 + g * 8 + 2 * pr;
                    d[pr] = (unsigned)f2bf(U[k0 * 256 + col0 + t2])
                          | ((unsigned)f2bf(U[(k0 + 1) * 256 + col0 + t2]) << 16);
                }
                bfrag[t2][kk] = make_uint4(d[0], d[1], d[2], d[3]);
            }
        }
        #pragma unroll
        for (int t2 = 0; t2 < 2; ++t2)
            #pragma unroll
            for (int kk = 0; kk < 8; ++kk)
                asm volatile("" : "+v"(bfrag[t2][kk].x), "+v"(bfrag[t2][kk].y),
                                  "+v"(bfrag[t2][kk].z), "+v"(bfrag[t2][kk].w));

        const float2 wv2 = *(const float2*)&W[col0];
        const float2 bv2 = *(const float2*)&bias[col0];

        if (p == 1) {
            // re-zero h buffer 0 for layer 2 (first 1KB = 256 u32)
            if (tid < 256) ((unsigned int*)hbuf)[tid] = 0u;
        }
        __syncthreads();

        // sv prefetch for t=0 (xall/seq2 static during loop; uniform address)
        float2 svc = p ? seq2[0] : xall[0];

        for (int t = 0; t < T; ++t) {
            char* const hcur = hbase + ((t & 1) << 10);
            char* const hnxt = hbase + (((t & 1) ^ 1) << 10);

            // A-fragments: 8 x ds_read_b128, 8 distinct cells, x8 broadcast
            uint4 a[8];
            #pragma unroll
            for (int kk = 0; kk < 8; ++kk)
                a[kk] = *(const uint4*)(hcur + rd_off[kk]);

            // acc init = input projection + bias; rows 2..15 mirror 0..1 so
            // the duplicate C rows stay exactly consistent.
            f32x4 aA0, aA1;
            f32x4 aB0 = {0.f, 0.f, 0.f, 0.f}, aB1 = {0.f, 0.f, 0.f, 0.f};
            aA0[0] = fmaf(svc.x, wv2.x, bv2.x);
            aA0[1] = fmaf(svc.y, wv2.x, bv2.x);
            aA0[2] = aA0[0]; aA0[3] = aA0[1];
            aA1[0] = fmaf(svc.x, wv2.y, bv2.y);
            aA1[1] = fmaf(svc.y, wv2.y, bv2.y);
            aA1[2] = aA1[0]; aA1[3] = aA1[1];

            // 4 independent 4-deep MFMA chains (2 tiles x even/odd kk)
            #pragma unroll
            for (int kp = 0; kp < 4; ++kp) {
                aA0 = __builtin_amdgcn_mfma_f32_16x16x32_bf16(
                    as_s8(a[2 * kp]), as_s8(bfrag[0][2 * kp]), aA0, 0, 0, 0);
                aA1 = __builtin_amdgcn_mfma_f32_16x16x32_bf16(
                    as_s8(a[2 * kp]), as_s8(bfrag[1][2 * kp]), aA1, 0, 0, 0);
                aB0 = __builtin_amdgcn_mfma_f32_16x16x32_bf16(
                    as_s8(a[2 * kp + 1]), as_s8(bfrag[0][2 * kp + 1]), aB0, 0, 0, 0);
                aB1 = __builtin_amdgcn_mfma_f32_16x16x32_bf16(
                    as_s8(a[2 * kp + 1]), as_s8(bfrag[1][2 * kp + 1]), aB1, 0, 0, 0);
            }

            // prefetch sv for t+1 (uniform-address, static LDS)
            {
                const int tn = (t + 1 < T) ? t + 1 : 0;
                svc = p ? seq2[tn] : xall[tn];
            }

            // epilogue: only rows 0,1 are real
            const float h00 = fast_tanh(aA0[0] + aB0[0]);   // col0,   row0
            const float h01 = fast_tanh(aA0[1] + aB0[1]);   // col0,   row1
            const float h10 = fast_tanh(aA1[0] + aB1[0]);   // col0+1, row0
            const float h11 = fast_tanh(aA1[1] + aB1[1]);   // col0+1, row1
            unsigned pk0, pk1;
            asm("v_cvt_pk_bf16_f32 %0, %1, %2" : "=v"(pk0) : "v"(h00), "v"(h10));
            asm("v_cvt_pk_bf16_f32 %0, %1, %2" : "=v"(pk1) : "v"(h01), "v"(h11));

            if (g == 0) {
                *(unsigned int*)(hnxt + wr_off[0]) = pk0;   // row 0
                *(unsigned int*)(hnxt + wr_off[1]) = pk1;   // row 1
                if (t == T - 1) {
                    if (p == 0) {
                        seq2[col0]     = make_float2(h00, h01);
                        seq2[col0 + 1] = make_float2(h10, h11);
                    } else {
                        *(float2*)&h2out[(b0 + 0) * 256 + col0] = make_float2(h00, h10);
                        *(float2*)&h2out[(b0 + 1) * 256 + col0] = make_float2(h01, h11);
                    }
                }
            }
            __syncthreads();
        }
    }
}

// Tiny MLP head: one block per batch row, 128 threads.
__global__ __launch_bounds__(128) void mlp_kernel(
    const float* __restrict__ h2,
    const float* __restrict__ Wd1, const float* __restrict__ bd1,
    const float* __restrict__ Wd2, const float* __restrict__ bd2,
    const float* __restrict__ Wd3, const float* __restrict__ bd3,
    const float* __restrict__ Wd4, const float* __restrict__ bd4,
    float* __restrict__ out)
{
    const int b   = blockIdx.x;
    const int tid = threadIdx.x;

    __shared__ float hin[256];
    __shared__ float z1[128];
    __shared__ float z2[64];
    __shared__ float z3[32];

    hin[tid]       = h2[b * 256 + tid];
    hin[tid + 128] = h2[b * 256 + tid + 128];
    __syncthreads();

    {
        float a = bd1[tid];
#pragma unroll 8
        for (int i = 0; i < 256; ++i) a += hin[i] * Wd1[i * 128 + tid];
        z1[tid] = fmaxf(a, 0.0f);
    }
    __syncthreads();
    if (tid < 64) {
        float a = bd2[tid];
#pragma unroll 8
        for (int i = 0; i < 128; ++i) a += z1[i] * Wd2[i * 64 + tid];
        z2[tid] = fmaxf(a, 0.0f);
    }
    __syncthreads();
    if (tid < 32) {
        float a = bd3[tid];
#pragma unroll 8
        for (int i = 0; i < 64; ++i) a += z2[i] * Wd3[i * 32 + tid];
        z3[tid] = fmaxf(a, 0.0f);
    }
    __syncthreads();
    if (tid < NCLS) {
        float a = bd4[tid];
#pragma unroll
        for (int i = 0; i < 32; ++i) a += z3[i] * Wd4[i * NCLS + tid];
        out[b * NCLS + tid] = a;
    }
}

extern "C" void kernel_launch(void* const* d_in, const int* in_sizes, int n_in,
                              void* d_out, int out_size, void* d_ws, size_t ws_size,
                              hipStream_t stream) {
    const float* x   = (const float*)d_in[0];
    const float* W1  = (const float*)d_in[1];
    const float* U1  = (const float*)d_in[2];
    const float* b1  = (const float*)d_in[3];
    const float* W2  = (const float*)d_in[4];
    const float* U2  = (const float*)d_in[5];
    const float* b2  = (const float*)d_in[6];
    const float* Wd1 = (const float*)d_in[7];
    const float* bd1 = (const float*)d_in[8];
    const float* Wd2 = (const float*)d_in[9];
    const float* bd2 = (const float*)d_in[10];
    const float* Wd3 = (const float*)d_in[11];
    const float* bd3 = (const float*)d_in[12];
    const float* Wd4 = (const float*)d_in[13];
    const float* bd4 = (const float*)d_in[14];

    float* out = (float*)d_out;
    float* h2  = (float*)d_ws;        // 512*256 fp32

    rnn_fused_kernel<<<256, 512, 0, stream>>>(x, W1, U1, b1, W2, U2, b2, h2);
    mlp_kernel<<<512, 128, 0, stream>>>(h2, Wd1, bd1, Wd2, bd2, Wd3, bd3, Wd4, bd4, out);
}